// Round 13
// baseline (46.988 us; speedup 1.0000x reference)
//
#include <hip/hip_runtime.h>

// Probabilistic Conway forward prop.
// in:  (32, 1024, 1024) float32; out = pmf3 + pmf2 * p_self over 8 Moore
// neighbors (torus), Poisson-binomial pmf truncated at k=3.
//
// Round 13: persistent-ish blocks + distance-1 load stagger. 2048 blocks
// (8/CU, all resident at t=0 -> no dispatch churn), RPB=16 rows/block
// (read redundancy 1.125x). Loads issued in groups: rows 0-9 upfront,
// 10-13 after phase A, 14-17 after phase B -- each compute phase runs with
// the NEXT phase's loads in flight (round 12 only overlapped within one
// upfront burst). Wrap addressing is all-SGPR (row base wave-uniform).
// Packed f32x2 core (stride-2 row pairs), NT stores, 36-lane edge gather,
// XCD swizzle (2048 % 8 == 0).

#define H 1024
#define W 1024
#define RPB 16
#define NR (RPB + 2)

typedef float f32x4 __attribute__((ext_vector_type(4)));
typedef float f32x2 __attribute__((ext_vector_type(2)));

__global__ __launch_bounds__(256) void prob_conway_kernel(
    const float* __restrict__ in, float* __restrict__ out) {
    const int nblk = 32 * (H / RPB);       // 2048
    const int cpx  = nblk / 8;             // 256 blocks per XCD chunk
    const int bid  = blockIdx.x;
    const int s    = (bid & 7) * cpx + (bid >> 3);   // bijective swizzle

    const int plane = s >> 6;              // 64 row-groups per plane
    const int rg    = s & 63;
    const int r0    = rg * RPB;
    const int lane  = threadIdx.x & 63;
    const int c0    = threadIdx.x * 4;     // 256 threads cover 1024 cols

    const float* __restrict__ img = in + (size_t)plane * (H * W);
    float* __restrict__ o         = out + (size_t)plane * (H * W);

    // ---- gather load: lanes 0..35 fetch wave-edge halos for 18 rows ----
    const int wbase = (threadIdx.x >> 6) << 8;         // wave base col
    const int clw   = (wbase + W - 1) & (W - 1);
    const int crw   = (wbase + 256) & (W - 1);
    int gi = lane >> 1;
    gi = (gi < NR) ? gi : 0;                           // lanes >=36 duplicate
    const int grow = (r0 + gi - 1 + H) & (H - 1);
    const int gcol = (lane & 1) ? crw : clw;
    const float gv = img[(size_t)grow * W + gcol];

    float P[NR][6];

#define LOADROW(i)                                                         \
    {                                                                      \
        const int r = (r0 + (i) - 1 + H) & (H - 1);                        \
        const f32x4 v =                                                    \
            *reinterpret_cast<const f32x4*>(img + (size_t)r * W + c0);     \
        P[i][1] = v.x; P[i][2] = v.y; P[i][3] = v.z; P[i][4] = v.w;        \
    }

#define HALO(i)                                                            \
    {                                                                      \
        const float lv = __shfl_up(P[i][4], 1);                            \
        const float rv = __shfl_down(P[i][1], 1);                          \
        const float e  = __shfl(gv, 2 * (i) + ((lane == 63) ? 1 : 0));     \
        P[i][0] = (lane == 0)  ? e : lv;                                   \
        P[i][5] = (lane == 63) ? e : rv;                                   \
    }

    // packed factorized pmf over 4 output rows [obase .. obase+3],
    // using P rows [pbase .. pbase+5]; Q rows are stride-2 pairs.
#define PHASE(pbase, obase)                                                \
    {                                                                      \
        f32x2 Q[6][6];                                                     \
        _Pragma("unroll")                                                  \
        for (int i = 0; i < 4; ++i)                                        \
            _Pragma("unroll")                                              \
            for (int c = 0; c < 6; ++c)                                    \
                Q[i][c] = f32x2{P[(pbase) + i][c], P[(pbase) + i + 2][c]}; \
        _Pragma("unroll")                                                  \
        for (int k = 0; k < 2; ++k) {                                      \
            f32x2 v3[6][4];                                                \
            f32x2 dd[4][3];                                                \
            _Pragma("unroll")                                              \
            for (int jc = 0; jc < 6; ++jc) {                               \
                const f32x2 a  = Q[k][jc];                                 \
                const f32x2 b  = Q[k + 1][jc];                             \
                const f32x2 cc = Q[k + 2][jc];                             \
                const f32x2 qa = 1.0f - a, qb = 1.0f - b, qc = 1.0f - cc;  \
                const f32x2 d0 = qa * qc;                                  \
                const f32x2 d1 = qa * cc + a * qc;                         \
                const f32x2 d2 = a * cc;                                   \
                v3[jc][0] = d0 * qb;                                       \
                v3[jc][1] = d1 * qb + d0 * b;                              \
                v3[jc][2] = d2 * qb + d1 * b;                              \
                v3[jc][3] = d2 * b;                                        \
                if (jc >= 1 && jc <= 4) {                                  \
                    dd[jc - 1][0] = d0; dd[jc - 1][1] = d1;                \
                    dd[jc - 1][2] = d2;                                    \
                }                                                          \
            }                                                              \
            f32x2 res[4];                                                  \
            _Pragma("unroll")                                              \
            for (int x = 0; x < 4; ++x) {                                  \
                const f32x2* L = v3[x];                                    \
                const f32x2* R = v3[x + 2];                                \
                const f32x2* D = dd[x];                                    \
                const f32x2 w0 = L[0] * R[0];                              \
                const f32x2 w1 = L[1] * R[0] + L[0] * R[1];                \
                const f32x2 w2 = L[2] * R[0] + L[1] * R[1] + L[0] * R[2];  \
                const f32x2 w3 = L[3] * R[0] + L[2] * R[1] + L[1] * R[2]   \
                               + L[0] * R[3];                              \
                const f32x2 pmf2 = w2 * D[0] + w1 * D[1] + w0 * D[2];      \
                const f32x2 pmf3 = w3 * D[0] + w2 * D[1] + w1 * D[2];      \
                res[x] = pmf3 + pmf2 * Q[k + 1][x + 1];                    \
            }                                                              \
            const f32x4 lo = {res[0].x, res[1].x, res[2].x, res[3].x};     \
            const f32x4 hi = {res[0].y, res[1].y, res[2].y, res[3].y};     \
            __builtin_nontemporal_store(lo,                                \
                reinterpret_cast<f32x4*>(                                  \
                    o + (size_t)((obase) + k) * W + c0));                  \
            __builtin_nontemporal_store(hi,                                \
                reinterpret_cast<f32x4*>(                                  \
                    o + (size_t)((obase) + k + 2) * W + c0));              \
        }                                                                  \
    }

    // prologue: rows 0..9 in flight
    LOADROW(0) LOADROW(1) LOADROW(2) LOADROW(3) LOADROW(4)
    LOADROW(5) LOADROW(6) LOADROW(7) LOADROW(8) LOADROW(9)

    // phase A (rows 0..5 -> outs r0..r0+3); rows 6..9 still in flight
    HALO(0) HALO(1) HALO(2) HALO(3) HALO(4) HALO(5)
    PHASE(0, r0)

    LOADROW(10) LOADROW(11) LOADROW(12) LOADROW(13)

    // phase B (rows 4..9); rows 10..13 in flight
    HALO(6) HALO(7) HALO(8) HALO(9)
    PHASE(4, r0 + 4)

    LOADROW(14) LOADROW(15) LOADROW(16) LOADROW(17)

    // phase C (rows 8..13); rows 14..17 in flight
    HALO(10) HALO(11) HALO(12) HALO(13)
    PHASE(8, r0 + 8)

    // phase D (rows 12..17)
    HALO(14) HALO(15) HALO(16) HALO(17)
    PHASE(12, r0 + 12)

#undef LOADROW
#undef HALO
#undef PHASE
}

extern "C" void kernel_launch(void* const* d_in, const int* in_sizes, int n_in,
                              void* d_out, int out_size, void* d_ws, size_t ws_size,
                              hipStream_t stream) {
    const float* in = (const float*)d_in[0];
    float* out = (float*)d_out;
    dim3 grid(32 * (H / RPB));   // 2048 blocks
    dim3 block(256);
    prob_conway_kernel<<<grid, block, 0, stream>>>(in, out);
}

// Round 15
// 44.959 us; speedup vs baseline: 1.0451x; 1.0451x over previous
//
#include <hip/hip_runtime.h>

// Probabilistic Conway forward prop.
// in:  (32, 1024, 1024) float32; out = pmf3 + pmf2 * p_self over 8 Moore
// neighbors (torus), Poisson-binomial pmf truncated at k=3.
//
// Round 15: grid-stride persistent blocks + cross-iteration prefetch +
// per-XCD L2-resident planes. Round 11's full grid was device-co-resident ->
// global lockstep (load burst / compute burst, memory pipe idle half the
// time). Now: 2048 blocks x 4 iterations. Block bid: xcd=bid&7, rg=bid>>3;
// iteration it processes plane it*8+xcd. Each XCD reads ONE 4 MiB plane per
// iteration (= its private L2), so stencil row redundancy is L2-served.
// While computing iteration it, iteration it+1's 7 loads (next plane) are in
// flight via a double register buffer (distance-1 pipeline; loop fully
// unrolled so all buffer indexing is static). Packed f32x2 pmf core
// (stride-2 row pairs), shfl halos + 1 gather, safe builtin NT stores.
// NOTE: cache-bypass asm stores are permanently dead: harness poisons d_out
// (0xAA) into caches before timing; bypass writes leave stale poison lines
// that the readback then sees (round 8 + round 14 failures).

#define H 1024
#define W 1024
#define RPT 4
#define NROWS 6
#define ITERS 4

typedef float f32x4 __attribute__((ext_vector_type(4)));
typedef float f32x2 __attribute__((ext_vector_type(2)));

struct Consume {
    // everything needed to turn one loaded 6-row window into 4 output rows
    int lane, c0, r0;
    float* o;                          // plane output base

    __device__ __forceinline__ void run(const f32x4 (&buf)[NROWS], float gv) {
        float P[NROWS][6];
#pragma unroll
        for (int i = 0; i < NROWS; ++i) {
            P[i][1] = buf[i].x; P[i][2] = buf[i].y;
            P[i][3] = buf[i].z; P[i][4] = buf[i].w;
        }
#pragma unroll
        for (int i = 0; i < NROWS; ++i) {
            const float lv = __shfl_up(P[i][4], 1);
            const float rv = __shfl_down(P[i][1], 1);
            const float e  = __shfl(gv, 2 * i + ((lane == 63) ? 1 : 0));
            P[i][0] = (lane == 0)  ? e : lv;
            P[i][5] = (lane == 63) ? e : rv;
        }
        // pack rows at stride 2: Q[i] = (P[i], P[i+2])
        f32x2 Q[4][6];
#pragma unroll
        for (int i = 0; i < 4; ++i)
#pragma unroll
            for (int c = 0; c < 6; ++c)
                Q[i][c] = f32x2{P[i][c], P[i + 2][c]};
#pragma unroll
        for (int k = 0; k < 2; ++k) {
            f32x2 v3[6][4];
            f32x2 dd[4][3];
#pragma unroll
            for (int jc = 0; jc < 6; ++jc) {
                const f32x2 a  = Q[k][jc];
                const f32x2 b  = Q[k + 1][jc];
                const f32x2 cc = Q[k + 2][jc];
                const f32x2 qa = 1.0f - a, qb = 1.0f - b, qc = 1.0f - cc;
                const f32x2 d0 = qa * qc;
                const f32x2 d1 = qa * cc + a * qc;
                const f32x2 d2 = a * cc;
                v3[jc][0] = d0 * qb;
                v3[jc][1] = d1 * qb + d0 * b;
                v3[jc][2] = d2 * qb + d1 * b;
                v3[jc][3] = d2 * b;
                if (jc >= 1 && jc <= 4) {
                    dd[jc - 1][0] = d0; dd[jc - 1][1] = d1; dd[jc - 1][2] = d2;
                }
            }
            f32x2 res[4];
#pragma unroll
            for (int x = 0; x < 4; ++x) {
                const f32x2* L = v3[x];
                const f32x2* R = v3[x + 2];
                const f32x2* D = dd[x];
                const f32x2 w0 = L[0] * R[0];
                const f32x2 w1 = L[1] * R[0] + L[0] * R[1];
                const f32x2 w2 = L[2] * R[0] + L[1] * R[1] + L[0] * R[2];
                const f32x2 w3 = L[3] * R[0] + L[2] * R[1] + L[1] * R[2]
                               + L[0] * R[3];
                const f32x2 pmf2 = w2 * D[0] + w1 * D[1] + w0 * D[2];
                const f32x2 pmf3 = w3 * D[0] + w2 * D[1] + w1 * D[2];
                res[x] = pmf3 + pmf2 * Q[k + 1][x + 1];
            }
            const f32x4 lo = {res[0].x, res[1].x, res[2].x, res[3].x};
            const f32x4 hi = {res[0].y, res[1].y, res[2].y, res[3].y};
            __builtin_nontemporal_store(
                lo, reinterpret_cast<f32x4*>(o + (size_t)(r0 + k) * W + c0));
            __builtin_nontemporal_store(
                hi, reinterpret_cast<f32x4*>(o + (size_t)(r0 + k + 2) * W + c0));
        }
    }
};

__global__ __launch_bounds__(256) void prob_conway_kernel(
    const float* __restrict__ in, float* __restrict__ out) {
    const int bid  = blockIdx.x;           // 0..2047
    const int xcd  = bid & 7;              // XCD (round-robin dispatch)
    const int rg   = bid >> 3;             // 0..255 row-group within plane
    const int r0   = rg * RPT;
    const int lane = threadIdx.x & 63;
    const int c0   = threadIdx.x * 4;

    // halo gather addressing (plane-independent)
    const int wbase = (threadIdx.x >> 6) << 8;
    const int clw   = (wbase + W - 1) & (W - 1);
    const int crw   = (wbase + 256) & (W - 1);
    int gi = lane >> 1;
    gi = (gi < NROWS) ? gi : 0;
    const int grow = (r0 + gi - 1 + H) & (H - 1);
    const int gcol = (lane & 1) ? crw : clw;
    const size_t goff = (size_t)grow * W + gcol;

    // wrapped row offsets within a plane (wave-uniform)
    size_t rowoff[NROWS];
#pragma unroll
    for (int i = 0; i < NROWS; ++i)
        rowoff[i] = (size_t)((r0 + i - 1 + H) & (H - 1)) * W + c0;

    f32x4 bufA[NROWS], bufB[NROWS];
    float gvA, gvB;

#define ISSUE(buf, gvv, it_next)                                          \
    {                                                                     \
        const float* img = in + (size_t)((it_next) * 8 + xcd) * (H * W);  \
        _Pragma("unroll")                                                 \
        for (int i = 0; i < NROWS; ++i)                                   \
            buf[i] = *reinterpret_cast<const f32x4*>(img + rowoff[i]);    \
        gvv = img[goff];                                                  \
    }

    ISSUE(bufA, gvA, 0)

    Consume cns;
    cns.lane = lane; cns.c0 = c0; cns.r0 = r0;

#pragma unroll
    for (int it = 0; it < ITERS; ++it) {
        if (it + 1 < ITERS) {
            if ((it & 1) == 0) ISSUE(bufB, gvB, it + 1)
            else               ISSUE(bufA, gvA, it + 1)
        }
        cns.o = out + (size_t)(it * 8 + xcd) * (H * W);
        if ((it & 1) == 0) cns.run(bufA, gvA);
        else               cns.run(bufB, gvB);
    }
#undef ISSUE
}

extern "C" void kernel_launch(void* const* d_in, const int* in_sizes, int n_in,
                              void* d_out, int out_size, void* d_ws, size_t ws_size,
                              hipStream_t stream) {
    const float* in = (const float*)d_in[0];
    float* out = (float*)d_out;
    dim3 grid(2048);   // 8 XCD x 256 row-groups; 4 planes per block
    dim3 block(256);
    prob_conway_kernel<<<grid, block, 0, stream>>>(in, out);
}

// Round 16
// 44.619 us; speedup vs baseline: 1.0531x; 1.0076x over previous
//
#include <hip/hip_runtime.h>

// Probabilistic Conway forward prop.
// in:  (32, 1024, 1024) float32; out = pmf3 + pmf2 * p_self over 8 Moore
// neighbors (torus), Poisson-binomial pmf truncated at k=3.
//
// Round 16: A/B discriminator -- EXACT round-12 structure (best, 43.8 us)
// with ONE change: plain cached stores instead of __builtin_nontemporal_store.
// Theory: R15 proved load latency isn't the binder (distance-1 prefetch was
// neutral); the NT no-allocate write stream may drain slower than cached
// write-back (fillBuffer with plain writes hits ~7 TB/s in our profiles),
// backpressuring VMEM issue at the stores. If this wins -> NT was throttling;
// if it regresses (FETCH up, dur ~46-49) -> round 12 is the practical
// ceiling. Everything else identical: two 4-row halves, loads upfront,
// packed f32x2 core (stride-2 row pairs), shfl halos + 1 gather, XCD
// swizzle, fast-path addressing.

#define H 1024
#define W 1024
#define RPB 8            // output rows per block (two halves of 4)
#define NR (RPB + 2)     // rows loaded: r0-1 .. r0+8

typedef float f32x4 __attribute__((ext_vector_type(4)));
typedef float f32x2 __attribute__((ext_vector_type(2)));

__global__ __launch_bounds__(256) void prob_conway_kernel(
    const float* __restrict__ in, float* __restrict__ out) {
    const int nblk = 32 * (H / RPB);       // 4096
    const int cpx  = nblk / 8;             // 512 blocks per XCD chunk
    const int bid  = blockIdx.x;
    const int s    = (bid & 7) * cpx + (bid >> 3);   // bijective swizzle

    const int plane = s >> 7;              // 128 row-groups per plane
    const int rg    = s & 127;
    const int r0    = rg * RPB;
    const int lane  = threadIdx.x & 63;
    const int c0    = threadIdx.x * 4;     // 256 threads cover 1024 cols

    const float* __restrict__ img = in + (size_t)plane * (H * W);
    float* __restrict__ o         = out + (size_t)plane * (H * W);

    // ---- gather load: lanes 0..19 fetch wave-edge halos for 10 rows ----
    const int wbase = (threadIdx.x >> 6) << 8;         // wave base col
    const int clw   = (wbase + W - 1) & (W - 1);
    const int crw   = (wbase + 256) & (W - 1);
    int gi = lane >> 1;
    gi = (gi < NR) ? gi : 0;                           // lanes >=20 duplicate
    const int grow = (r0 + gi - 1 + H) & (H - 1);
    const int gcol = (lane & 1) ? crw : clw;
    const float gv = img[(size_t)grow * W + gcol];

    // ---- vector loads: 10 rows x float4, all issued upfront ----
    float P[NR][6];
    if (rg != 0 && rg != 127) {
        const float* rp = img + (size_t)(r0 - 1) * W + c0;
#pragma unroll
        for (int i = 0; i < NR; ++i) {
            const f32x4 v = *reinterpret_cast<const f32x4*>(rp);
            P[i][1] = v.x; P[i][2] = v.y; P[i][3] = v.z; P[i][4] = v.w;
            rp += W;
        }
    } else {
#pragma unroll
        for (int i = 0; i < NR; ++i) {
            const int r = (r0 + i - 1 + H) & (H - 1);
            const f32x4 v =
                *reinterpret_cast<const f32x4*>(img + (size_t)r * W + c0);
            P[i][1] = v.x; P[i][2] = v.y; P[i][3] = v.z; P[i][4] = v.w;
        }
    }

    // halo distribute for one row (interior via shfl, wave edge via gather)
#define HALO(i)                                                         \
    {                                                                   \
        const float lv = __shfl_up(P[i][4], 1);                         \
        const float rv = __shfl_down(P[i][1], 1);                       \
        const float e  = __shfl(gv, 2 * (i) + ((lane == 63) ? 1 : 0));  \
        P[i][0] = (lane == 0)  ? e : lv;                                \
        P[i][5] = (lane == 63) ? e : rv;                                \
    }

    // packed factorized pmf for one half; Q rows are stride-2 pairs.
    // outputs: k=0 -> rows (base, base+2); k=1 -> rows (base+1, base+3)
#define COMPUTE_HALF(Q, base)                                           \
    _Pragma("unroll")                                                   \
    for (int k = 0; k < 2; ++k) {                                       \
        f32x2 v3[6][4];                                                 \
        f32x2 dd[4][3];                                                 \
        _Pragma("unroll")                                               \
        for (int jc = 0; jc < 6; ++jc) {                                \
            const f32x2 a  = Q[k][jc];                                  \
            const f32x2 b  = Q[k + 1][jc];                              \
            const f32x2 cc = Q[k + 2][jc];                              \
            const f32x2 qa = 1.0f - a, qb = 1.0f - b, qc = 1.0f - cc;   \
            const f32x2 d0 = qa * qc;                                   \
            const f32x2 d1 = qa * cc + a * qc;                          \
            const f32x2 d2 = a * cc;                                    \
            v3[jc][0] = d0 * qb;                                        \
            v3[jc][1] = d1 * qb + d0 * b;                               \
            v3[jc][2] = d2 * qb + d1 * b;                               \
            v3[jc][3] = d2 * b;                                         \
            if (jc >= 1 && jc <= 4) {                                   \
                dd[jc - 1][0] = d0; dd[jc - 1][1] = d1;                 \
                dd[jc - 1][2] = d2;                                     \
            }                                                           \
        }                                                               \
        f32x2 res[4];                                                   \
        _Pragma("unroll")                                               \
        for (int x = 0; x < 4; ++x) {                                   \
            const f32x2* L = v3[x];                                     \
            const f32x2* R = v3[x + 2];                                 \
            const f32x2* D = dd[x];                                     \
            const f32x2 w0 = L[0] * R[0];                               \
            const f32x2 w1 = L[1] * R[0] + L[0] * R[1];                 \
            const f32x2 w2 = L[2] * R[0] + L[1] * R[1] + L[0] * R[2];   \
            const f32x2 w3 = L[3] * R[0] + L[2] * R[1] + L[1] * R[2]    \
                           + L[0] * R[3];                               \
            const f32x2 pmf2 = w2 * D[0] + w1 * D[1] + w0 * D[2];       \
            const f32x2 pmf3 = w3 * D[0] + w2 * D[1] + w1 * D[2];       \
            res[x] = pmf3 + pmf2 * Q[k + 1][x + 1];                     \
        }                                                               \
        const f32x4 lo = {res[0].x, res[1].x, res[2].x, res[3].x};      \
        const f32x4 hi = {res[0].y, res[1].y, res[2].y, res[3].y};      \
        *reinterpret_cast<f32x4*>(                                      \
            o + (size_t)((base) + k) * W + c0) = lo;                    \
        *reinterpret_cast<f32x4*>(                                      \
            o + (size_t)((base) + k + 2) * W + c0) = hi;                \
    }

    // ---- phase A: rows 0..5 (output rows r0 .. r0+3) ----
    HALO(0) HALO(1) HALO(2) HALO(3) HALO(4) HALO(5)
    {
        f32x2 QA[4][6];
#pragma unroll
        for (int i = 0; i < 4; ++i)
#pragma unroll
            for (int c = 0; c < 6; ++c)
                QA[i][c] = f32x2{P[i][c], P[i + 2][c]};
        COMPUTE_HALF(QA, r0)
    }

    // ---- phase B: rows 6..9 (output rows r0+4 .. r0+7) ----
    HALO(6) HALO(7) HALO(8) HALO(9)
    {
        f32x2 QB[4][6];
#pragma unroll
        for (int i = 0; i < 4; ++i)
#pragma unroll
            for (int c = 0; c < 6; ++c)
                QB[i][c] = f32x2{P[i + 4][c], P[i + 6][c]};
        COMPUTE_HALF(QB, r0 + 4)
    }

#undef HALO
#undef COMPUTE_HALF
}

extern "C" void kernel_launch(void* const* d_in, const int* in_sizes, int n_in,
                              void* d_out, int out_size, void* d_ws, size_t ws_size,
                              hipStream_t stream) {
    const float* in = (const float*)d_in[0];
    float* out = (float*)d_out;
    dim3 grid(32 * (H / RPB));   // 4096 blocks
    dim3 block(256);
    prob_conway_kernel<<<grid, block, 0, stream>>>(in, out);
}